// Round 1
// baseline (121.134 us; speedup 1.0000x reference)
//
#include <hip/hip_runtime.h>

// FeatureShader: pytorch3d softmax_rgb_blend + TexturesVertex barycentric gather.
// N,H,W,K,C = 4,256,256,8,16. One thread per pixel (N*H*W = 262144 pixels).
//
// Numerics: GAMMA=1e-4 makes exp((z-zmax)/g) collapse to ~one dominant k per
// pixel; SIGMA=1e-4 saturates the sigmoid to {0,1}. We compute the FULL
// denominator (all 8 w_k, cheap, no gathers), then skip the gather for any
// w_k <= denom*1e-7 -> error bound ~8e-7*|texel| << 0.1256 absmax threshold.

constexpr int KK = 8;
constexpr int CC = 16;

__global__ __launch_bounds__(256) void feature_shader(
    const float* __restrict__ dists,
    const float* __restrict__ zbuf,
    const float* __restrict__ bary,
    const float* __restrict__ vfeat,
    const float* __restrict__ bg,
    const int*   __restrict__ p2f,
    const int*   __restrict__ faces,
    float* __restrict__ out,
    int npix)
{
    const float INV_SIGMA = 1e4f;          // 1/SIGMA
    const float INV_GAMMA = 1e4f;          // 1/GAMMA
    const float EPS       = 1e-10f;
    const float ZFAR      = 100.f;
    const float INV_SPAN  = 1.f / 99.f;    // 1/(ZFAR-ZNEAR)

    int p = blockIdx.x * blockDim.x + threadIdx.x;
    if (p >= npix) return;

    // Vectorized per-pixel loads (8 consecutive elements each, 32B aligned).
    const float4* z4 = (const float4*)(zbuf  + (size_t)p * KK);
    const float4* d4 = (const float4*)(dists + (size_t)p * KK);
    const int4*   f4 = (const int4*)  (p2f   + (size_t)p * KK);
    float4 za = z4[0], zb = z4[1];
    float4 da = d4[0], db = d4[1];
    int4   fa = f4[0], fb = f4[1];

    float z[8] = {za.x, za.y, za.z, za.w, zb.x, zb.y, zb.z, zb.w};
    float d[8] = {da.x, da.y, da.z, da.w, db.x, db.y, db.z, db.w};
    int   f[8] = {fa.x, fa.y, fa.z, fa.w, fb.x, fb.y, fb.z, fb.w};

    // z_inv and its clipped max
    float zinv[8];
    float m = EPS;
    #pragma unroll
    for (int k = 0; k < 8; ++k) {
        float v = (f[k] >= 0) ? (ZFAR - z[k]) * INV_SPAN : 0.f;
        zinv[k] = v;
        m = fmaxf(m, v);
    }

    float delta = fmaxf(__expf((EPS - m) * INV_GAMMA), EPS);

    // Full softmax weights + exact denominator (no gathers needed here).
    float w[8];
    float denom = delta;
    #pragma unroll
    for (int k = 0; k < 8; ++k) {
        float e    = __expf((zinv[k] - m) * INV_GAMMA);        // <= 1
        float prob = (f[k] >= 0) ? (1.f / (1.f + __expf(d[k] * INV_SIGMA))) : 0.f;
        float wk   = prob * e;
        w[k] = wk;
        denom += wk;
    }
    float thr = denom * 1e-7f;   // skip texel gather below this (error ~1e-6 rel)

    float acc[16];
    #pragma unroll
    for (int c = 0; c < 16; ++c) acc[c] = 0.f;

    // Gather + blend only for contributing slots (~1-2 of 8 per pixel).
    #pragma unroll
    for (int k = 0; k < 8; ++k) {
        if (w[k] > thr) {
            int idx = f[k];
            int v0 = faces[idx * 3 + 0];
            int v1 = faces[idx * 3 + 1];
            int v2 = faces[idx * 3 + 2];
            const float* bp = bary + (size_t)(p * KK + k) * 3;
            float b0 = bp[0] * w[k];
            float b1 = bp[1] * w[k];
            float b2 = bp[2] * w[k];
            const float4* t0 = (const float4*)(vfeat + (size_t)v0 * CC);
            const float4* t1 = (const float4*)(vfeat + (size_t)v1 * CC);
            const float4* t2 = (const float4*)(vfeat + (size_t)v2 * CC);
            #pragma unroll
            for (int j = 0; j < 4; ++j) {
                float4 a0 = t0[j], a1 = t1[j], a2 = t2[j];
                acc[j * 4 + 0] += b0 * a0.x + b1 * a1.x + b2 * a2.x;
                acc[j * 4 + 1] += b0 * a0.y + b1 * a1.y + b2 * a2.y;
                acc[j * 4 + 2] += b0 * a0.z + b1 * a1.z + b2 * a2.z;
                acc[j * 4 + 3] += b0 * a0.w + b1 * a1.w + b2 * a2.w;
            }
        }
    }

    float inv_den = 1.f / denom;
    float4* out4 = (float4*)(out + (size_t)p * CC);
    const float4* bg4 = (const float4*)bg;
    #pragma unroll
    for (int j = 0; j < 4; ++j) {
        float4 g = bg4[j];
        float4 o;
        o.x = (acc[j * 4 + 0] + delta * g.x) * inv_den;
        o.y = (acc[j * 4 + 1] + delta * g.y) * inv_den;
        o.z = (acc[j * 4 + 2] + delta * g.z) * inv_den;
        o.w = (acc[j * 4 + 3] + delta * g.w) * inv_den;
        out4[j] = o;
    }
}

extern "C" void kernel_launch(void* const* d_in, const int* in_sizes, int n_in,
                              void* d_out, int out_size, void* d_ws, size_t ws_size,
                              hipStream_t stream) {
    const float* dists = (const float*)d_in[0];
    const float* zbuf  = (const float*)d_in[1];
    const float* bary  = (const float*)d_in[2];
    const float* vfeat = (const float*)d_in[3];
    const float* bg    = (const float*)d_in[4];
    const int*   p2f   = (const int*)d_in[5];
    const int*   faces = (const int*)d_in[6];
    float* out = (float*)d_out;

    int npix = in_sizes[0] / KK;           // N*H*W = 262144
    int block = 256;
    int grid = (npix + block - 1) / block; // 1024 blocks

    hipLaunchKernelGGL(feature_shader, dim3(grid), dim3(block), 0, stream,
                       dists, zbuf, bary, vfeat, bg, p2f, faces, out, npix);
}

// Round 2
// 120.543 us; speedup vs baseline: 1.0049x; 1.0049x over previous
//
#include <hip/hip_runtime.h>

// FeatureShader: pytorch3d softmax_rgb_blend + TexturesVertex barycentric gather.
// N,H,W,K,C = 4,256,256,8,16.
//
// R2 layout: one thread per (pixel, k) slot -> 2M threads, 32 waves/CU.
// - softmax max/denom: 3-step __shfl_xor butterfly over the 8-lane group
// - gather: single predicated region (~17% lanes active)
// - channel sum over k: 3-stage reduce-scatter shuffle; lane k ends with
//   channels [2k,2k+1] -> ((float2*)out)[t] is fully coalesced.

constexpr int KK = 8;
constexpr int CC = 16;

__global__ __launch_bounds__(256) void feature_shader(
    const float* __restrict__ dists,
    const float* __restrict__ zbuf,
    const float* __restrict__ bary,
    const float* __restrict__ vfeat,
    const float* __restrict__ bg,
    const int*   __restrict__ p2f,
    const int*   __restrict__ faces,
    float* __restrict__ out,
    int n)   // n = N*H*W*K
{
    const float INV_SIGMA = 1e4f;          // 1/SIGMA
    const float INV_GAMMA = 1e4f;          // 1/GAMMA
    const float EPS       = 1e-10f;
    const float ZFAR      = 100.f;
    const float INV_SPAN  = 1.f / 99.f;    // 1/(ZFAR-ZNEAR)

    int t = blockIdx.x * blockDim.x + threadIdx.x;
    if (t >= n) return;
    int k = t & (KK - 1);

    // Perfectly coalesced per-slot loads.
    float z  = zbuf[t];
    float dd = dists[t];
    int   f  = p2f[t];

    float zinv = (f >= 0) ? (ZFAR - z) * INV_SPAN : 0.f;

    // Group max over the 8-lane k-group.
    float m = zinv;
    m = fmaxf(m, __shfl_xor(m, 1));
    m = fmaxf(m, __shfl_xor(m, 2));
    m = fmaxf(m, __shfl_xor(m, 4));
    m = fmaxf(m, EPS);

    float delta = fmaxf(__expf((EPS - m) * INV_GAMMA), EPS);
    float prob  = (f >= 0) ? 1.f / (1.f + __expf(dd * INV_SIGMA)) : 0.f;
    float w     = prob * __expf((zinv - m) * INV_GAMMA);

    // Group sum -> denominator (uniform across the group after butterfly).
    float denom = w;
    denom += __shfl_xor(denom, 1);
    denom += __shfl_xor(denom, 2);
    denom += __shfl_xor(denom, 4);
    denom += delta;
    float thr = denom * 1e-7f;   // skip gather below this; error ~1e-6 abs

    float acc[CC];
    #pragma unroll
    for (int c = 0; c < CC; ++c) acc[c] = 0.f;

    // Single predicated gather region (avg ~1.4 of 8 lanes active per group).
    if (w > thr) {
        int v0 = faces[f * 3 + 0];
        int v1 = faces[f * 3 + 1];
        int v2 = faces[f * 3 + 2];
        const float* bp = bary + (size_t)t * 3;
        float b0 = bp[0] * w, b1 = bp[1] * w, b2 = bp[2] * w;
        const float4* t0 = (const float4*)(vfeat + (size_t)v0 * CC);
        const float4* t1 = (const float4*)(vfeat + (size_t)v1 * CC);
        const float4* t2 = (const float4*)(vfeat + (size_t)v2 * CC);
        #pragma unroll
        for (int j = 0; j < 4; ++j) {
            float4 a0 = t0[j], a1 = t1[j], a2 = t2[j];
            acc[j * 4 + 0] = b0 * a0.x + b1 * a1.x + b2 * a2.x;
            acc[j * 4 + 1] = b0 * a0.y + b1 * a1.y + b2 * a2.y;
            acc[j * 4 + 2] = b0 * a0.z + b1 * a1.z + b2 * a2.z;
            acc[j * 4 + 3] = b0 * a0.w + b1 * a1.w + b2 * a2.w;
        }
    }

    // Reduce-scatter across the 8-lane group: 16 -> 8 -> 4 -> 2 channels.
    // Stage distance d: lane keeps low half of its block if (k & d) == 0.
    {   // d=4: 16 -> 8
        bool low = (k & 4) == 0;
        float nxt[8];
        #pragma unroll
        for (int i = 0; i < 8; ++i) {
            float send = low ? acc[8 + i] : acc[i];
            float recv = __shfl_xor(send, 4);
            nxt[i] = (low ? acc[i] : acc[8 + i]) + recv;
        }
        #pragma unroll
        for (int i = 0; i < 8; ++i) acc[i] = nxt[i];
    }
    {   // d=2: 8 -> 4
        bool low = (k & 2) == 0;
        float nxt[4];
        #pragma unroll
        for (int i = 0; i < 4; ++i) {
            float send = low ? acc[4 + i] : acc[i];
            float recv = __shfl_xor(send, 2);
            nxt[i] = (low ? acc[i] : acc[4 + i]) + recv;
        }
        #pragma unroll
        for (int i = 0; i < 4; ++i) acc[i] = nxt[i];
    }
    {   // d=1: 4 -> 2; lane k ends with channels [2k, 2k+1]
        bool low = (k & 1) == 0;
        float nxt[2];
        #pragma unroll
        for (int i = 0; i < 2; ++i) {
            float send = low ? acc[2 + i] : acc[i];
            float recv = __shfl_xor(send, 1);
            nxt[i] = (low ? acc[i] : acc[2 + i]) + recv;
        }
        acc[0] = nxt[0];
        acc[1] = nxt[1];
    }

    float2 g = ((const float2*)bg)[k];
    float inv_den = 1.f / denom;
    float2 o;
    o.x = (acc[0] + delta * g.x) * inv_den;
    o.y = (acc[1] + delta * g.y) * inv_den;
    ((float2*)out)[t] = o;   // coalesced: element t covers out[p*16 + 2k ..]
}

extern "C" void kernel_launch(void* const* d_in, const int* in_sizes, int n_in,
                              void* d_out, int out_size, void* d_ws, size_t ws_size,
                              hipStream_t stream) {
    const float* dists = (const float*)d_in[0];
    const float* zbuf  = (const float*)d_in[1];
    const float* bary  = (const float*)d_in[2];
    const float* vfeat = (const float*)d_in[3];
    const float* bg    = (const float*)d_in[4];
    const int*   p2f   = (const int*)d_in[5];
    const int*   faces = (const int*)d_in[6];
    float* out = (float*)d_out;

    int n = in_sizes[0];                   // N*H*W*K = 2097152
    int block = 256;
    int grid = (n + block - 1) / block;    // 8192 blocks

    hipLaunchKernelGGL(feature_shader, dim3(grid), dim3(block), 0, stream,
                       dists, zbuf, bary, vfeat, bg, p2f, faces, out, n);
}